// Round 5
// baseline (190.161 us; speedup 1.0000x reference)
//
#include <hip/hip_runtime.h>

#define TSTEPS 128
#define NBATCH 2048
#define DIN    32
#define INV_PI 0.31830988618379067f

// ---- DPP helpers ----
template <int CTRL>
__device__ __forceinline__ float qperm(float v) {   // quad_perm, all lanes valid
    return __int_as_float(
        __builtin_amdgcn_mov_dpp(__float_as_int(v), CTRL, 0xF, 0xF, true));
}
template <int CTRL>
__device__ __forceinline__ float dpp_z(float v) {   // row shift, invalid -> 0
    return __int_as_float(__builtin_amdgcn_update_dpp(
        0, __float_as_int(v), CTRL, 0xF, 0xF, true));
}
template <int CTRL>
__device__ __forceinline__ float dpp_k(float oldv, float v) { // invalid -> keep old
    return __int_as_float(__builtin_amdgcn_update_dpp(
        __float_as_int(oldv), __float_as_int(v), CTRL, 0xF, 0xF, false));
}
// ctrl: quad_perm 0x00-0xFF; row_shl:N = 0x100+N (lane n <- n+N);
//       row_shr:N = 0x110+N (lane n <- n-N).

__device__ __forceinline__ float rcp_f(float x) { return __builtin_amdgcn_rcpf(x); }

// ================== Fused kernel: block-local proj + recurrence ==================
// Grid 512 x 256. Block handles batches B0..B0+3 for all 128 timesteps.
// Phase 1 (all 4 waves): proj[r][t*4+bl] = (1/pi)*(b_g[i] + x[t,B0+bl,:].W_g[i,:32])
//   r = g2*4+i, gate order g2: 0=f,1=o,2=i,3=u. Column-major in LDS.
// Phase 2 (wave 0): 16 lanes/batch (lane = bl*16 + g2*4 + i), DPP recurrence.
extern "C" __global__ void __launch_bounds__(256)
qlstm_fused(const float* __restrict__ x,
            const float* __restrict__ Wf, const float* __restrict__ bfp,
            const float* __restrict__ Wi, const float* __restrict__ bip,
            const float* __restrict__ Wu, const float* __restrict__ bup,
            const float* __restrict__ Wo, const float* __restrict__ bop,
            float* __restrict__ out)
{
    __shared__ float4 WL[16 * 8];            // 2 KB, row rr=g2*4+i
    __shared__ float  bias[16];
    __shared__ float  proj[16 * 512];        // 32 KB, [r][rl], rl = t*4+bl

    const int tid = threadIdx.x;
    const int B0  = blockIdx.x * 4;
    float* WLf = (float*)WL;

    // stage weights (pre-scaled by 1/pi), g2-major
    for (int idx = tid; idx < 512; idx += 256) {
        int rr = idx >> 5, k = idx & 31;
        int g2 = rr >> 2, i = rr & 3;
        const float* W = (g2 == 0) ? Wf : (g2 == 1) ? Wo : (g2 == 2) ? Wi : Wu;
        WLf[rr * 32 + k] = W[i * 36 + k] * INV_PI;
    }
    if (tid < 16) {
        int g2 = tid >> 2, i = tid & 3;
        const float* bp = (g2 == 0) ? bfp : (g2 == 1) ? bop : (g2 == 2) ? bip : bup;
        bias[tid] = bp[i] * INV_PI;
    }
    __syncthreads();

    // ---- phase 1: 2 rows per thread (rl = tid, tid+256) ----
#pragma unroll
    for (int j = 0; j < 2; ++j) {
        const int rl = tid + j * 256;        // 0..511
        const int t  = rl >> 2, b = rl & 3;
        const float4* xv = reinterpret_cast<const float4*>(
            x + ((size_t)t * NBATCH + (size_t)(B0 + b)) * DIN);
        float4 a[8];
#pragma unroll
        for (int k = 0; k < 8; ++k) a[k] = xv[k];
#pragma unroll
        for (int rr = 0; rr < 16; ++rr) {
            float s = bias[rr];
#pragma unroll
            for (int k = 0; k < 8; ++k) {
                float4 w = WL[rr * 8 + k];
                s = fmaf(a[k].x, w.x, s);
                s = fmaf(a[k].y, w.y, s);
                s = fmaf(a[k].z, w.z, s);
                s = fmaf(a[k].w, w.w, s);
            }
            proj[rr * 512 + rl] = s;
        }
    }
    __syncthreads();

    if (tid >= 64) return;                   // waves 1-3 done

    // ---- phase 2: wave 0 recurrence, 16 lanes per batch ----
    const int l  = tid;
    const int bl = l >> 4;                   // batch within block (0..3)
    const int r  = l & 15;
    const int g  = r >> 2;                   // 0=f,1=o,2=i,3=u
    const int i  = r & 3;
    const int bg = B0 + bl;
    const bool m1 = (i >= 1), m2 = (i >= 2);

    const float* Wg = (g == 0) ? Wf : (g == 1) ? Wo : (g == 2) ? Wi : Wu;
    float wh0 = Wg[i * 36 + 32 + (i ^ 0)] * INV_PI;
    float wh1 = Wg[i * 36 + 32 + (i ^ 1)] * INV_PI;
    float wh2 = Wg[i * 36 + 32 + (i ^ 2)] * INV_PI;
    float wh3 = Wg[i * 36 + 32 + (i ^ 3)] * INV_PI;
    // unified sigmoid/tanh: y = aa * rcp(1 + exp2(kk*q)) + cc
    const float kk = (g == 3) ? -2.8853900818f : -1.4426950409f;
    const float aa = (g == 3) ? 2.0f : 1.0f;
    const float cc = (g == 3) ? -1.0f : 0.0f;

    float ha = 0.f, hx1 = 0.f, hx2 = 0.f, hx3 = 0.f, cst = 0.f;

    const float* pb = proj + r * 512 + bl;   // lane's column base; step t at +4t
    float* outb = out + (size_t)bg * 4 + r;  // valid when r<4

    auto qstep = [&](float xp, int t) {
        float p = fmaf(wh3, hx3, fmaf(wh2, hx2, fmaf(wh1, hx1, fmaf(wh0, ha, xp))));
        // cos^2(pre) = 0.5 + 0.5*cos_rev(pre/pi)
        float fr = __builtin_amdgcn_fractf(p);
        float cs = __builtin_amdgcn_cosf(fr);
        float q  = fmaf(0.5f, cs, 0.5f);
        // prefix product over i within quad
        float s1 = qperm<0x90>(q);  q *= m1 ? s1 : 1.0f;
        float s2 = qperm<0x44>(q);  q *= m2 ? s2 : 1.0f;
        // per-lane activation
        float e1 = __builtin_amdgcn_exp2f(kk * q);
        float y  = fmaf(aa, rcp_f(1.0f + e1), cc);
        // combine at f-lanes
        float t1 = dpp_z<0x104>(y);          // f<-sig_o, i<-tanh_u
        float m_ = y * t1;                   // i-lanes: sig_i * tanh_u
        float t2 = dpp_z<0x108>(m_);         // f-lanes <- i*u
        cst = fmaf(y, cst, t2);              // f-lanes: f*c + i*u
        float e2 = __builtin_amdgcn_exp2f(-2.8853900818f * cst);
        float r2 = rcp_f(1.0f + e2);
        float o2 = t1 + t1;
        float hn = fmaf(o2, r2, -t1);        // o * tanh(c) at f-lanes
        if (r < 4) outb[(size_t)t * (NBATCH * 4)] = hn;
        // distribute h to all 16 lanes, xor layout
        float d1 = dpp_k<0x114>(hn, hn);     // lanes 4..7  <- 0..3
        float d2 = dpp_k<0x118>(d1, d1);     // lanes 8..15 <- 0..7
        ha  = d2;
        hx1 = qperm<0xB1>(d2);
        hx2 = qperm<0x4E>(d2);
        hx3 = qperm<0xB1>(hx2);
    };

    // 8-deep LDS->reg prefetch ring (static indexing)
    float xr[8];
#pragma unroll
    for (int k = 0; k < 8; ++k) xr[k] = pb[4 * k];

    for (int tg = 0; tg < TSTEPS / 8; ++tg) {
        const int tb = tg * 8;
#pragma unroll
        for (int k = 0; k < 8; ++k) {
            float xp = xr[k];
            int tn = tb + 8 + k;  if (tn > TSTEPS - 1) tn = TSTEPS - 1;
            xr[k] = pb[4 * tn];              // prefetch 8 ahead
            qstep(xp, tb + k);
        }
    }

    const size_t off = (size_t)TSTEPS * NBATCH * 4;
    if (r < 4) {
        out[off + (size_t)bg * 4 + r] = ha;                        // final hx
        out[off + (size_t)NBATCH * 4 + (size_t)bg * 4 + r] = cst;  // final cx
    }
}

extern "C" void kernel_launch(void* const* d_in, const int* in_sizes, int n_in,
                              void* d_out, int out_size, void* d_ws, size_t ws_size,
                              hipStream_t stream) {
    (void)in_sizes; (void)n_in; (void)out_size; (void)d_ws; (void)ws_size;
    const float* x  = (const float*)d_in[0];
    const float* Wf = (const float*)d_in[1];
    const float* bf = (const float*)d_in[2];
    // d_in[3] = pf: RZ phases drop out of the measurement -> unused
    const float* Wi = (const float*)d_in[4];
    const float* bi = (const float*)d_in[5];
    const float* Wu = (const float*)d_in[7];
    const float* bu = (const float*)d_in[8];
    const float* Wo = (const float*)d_in[10];
    const float* bo = (const float*)d_in[11];
    float* out = (float*)d_out;

    hipLaunchKernelGGL(qlstm_fused, dim3(NBATCH / 4), dim3(256), 0, stream,
                       x, Wf, bf, Wi, bi, Wu, bu, Wo, bo, out);
}

// Round 6
// 44.200 us; speedup vs baseline: 4.3023x; 4.3023x over previous
//
#include <hip/hip_runtime.h>

#define TSTEPS 128
#define NBATCH 2048
#define DIN    32
#define NROWS  (TSTEPS * NBATCH)
#define INV_PI 0.31830988618379067f

// ---- DPP helpers ----
template <int CTRL>
__device__ __forceinline__ float qperm(float v) {   // quad_perm, all lanes valid
    return __int_as_float(
        __builtin_amdgcn_mov_dpp(__float_as_int(v), CTRL, 0xF, 0xF, true));
}
template <int CTRL>
__device__ __forceinline__ float dpp_z(float v) {   // row shift, invalid -> 0
    return __int_as_float(__builtin_amdgcn_update_dpp(
        0, __float_as_int(v), CTRL, 0xF, 0xF, true));
}
template <int CTRL>
__device__ __forceinline__ float dpp_k(float oldv, float v) { // invalid -> keep old
    return __int_as_float(__builtin_amdgcn_update_dpp(
        __float_as_int(oldv), __float_as_int(v), CTRL, 0xF, 0xF, false));
}
// ctrl: quad_perm 0x00-0xFF; row_shl:N = 0x100+N (lane n <- n+N);
//       row_shr:N = 0x110+N (lane n <- n-N). 0x1B = quad XOR-3 [3,2,1,0].

__device__ __forceinline__ float rcp_f(float x) { return __builtin_amdgcn_rcpf(x); }
__device__ __forceinline__ float sigm(float q)  { return rcp_f(1.0f + __expf(-q)); }
__device__ __forceinline__ float tanh_f(float z){ return fmaf(2.0f, rcp_f(1.0f + __expf(-2.0f * z)), -1.0f); }
__device__ __forceinline__ float cos2(float x)  { float c = __cosf(x); return c * c; }

// ======================= Kernel A: x-projection GEMM =======================
// ws[row*16 + g2*4 + i] = (1/pi)*(b_g[i] + x[row,:] . W_g[i,0:32])
// gate order g2: 0=f, 1=o, 2=i, 3=u.   row = t*NBATCH + b
extern "C" __global__ void __launch_bounds__(256)
xproj_kernel(const float* __restrict__ x,
             const float* __restrict__ Wf, const float* __restrict__ bfp,
             const float* __restrict__ Wi, const float* __restrict__ bip,
             const float* __restrict__ Wu, const float* __restrict__ bup,
             const float* __restrict__ Wo, const float* __restrict__ bop,
             float* __restrict__ ws)
{
    __shared__ float4 WL[16 * 8];
    __shared__ float  bias[16];
    const int tid = threadIdx.x;
    float* WLf = (float*)WL;
    for (int idx = tid; idx < 512; idx += 256) {
        int rr = idx >> 5, k = idx & 31;
        int g2 = rr >> 2, i = rr & 3;
        const float* W = (g2 == 0) ? Wf : (g2 == 1) ? Wo : (g2 == 2) ? Wi : Wu;
        WLf[rr * 32 + k] = W[i * 36 + k] * INV_PI;
    }
    if (tid < 16) {
        int g2 = tid >> 2, i = tid & 3;
        const float* bp = (g2 == 0) ? bfp : (g2 == 1) ? bop : (g2 == 2) ? bip : bup;
        bias[tid] = bp[i] * INV_PI;
    }
    __syncthreads();

    const int row0 = blockIdx.x * 512 + tid;   // 2 rows/thread, stride 256
    const float4* xv = reinterpret_cast<const float4*>(x);
    float4 xa[2][8];
#pragma unroll
    for (int j = 0; j < 2; ++j) {
        int row = row0 + j * 256;
#pragma unroll
        for (int k = 0; k < 8; ++k) xa[j][k] = xv[row * 8 + k];
    }
    float acc[2][16];
#pragma unroll
    for (int rr = 0; rr < 16; ++rr) {
        float4 w[8];
#pragma unroll
        for (int k = 0; k < 8; ++k) w[k] = WL[rr * 8 + k];
#pragma unroll
        for (int j = 0; j < 2; ++j) {
            float s = bias[rr];
#pragma unroll
            for (int k = 0; k < 8; ++k) {
                s = fmaf(xa[j][k].x, w[k].x, s);
                s = fmaf(xa[j][k].y, w[k].y, s);
                s = fmaf(xa[j][k].z, w[k].z, s);
                s = fmaf(xa[j][k].w, w[k].w, s);
            }
            acc[j][rr] = s;
        }
    }
    float4* wsv = reinterpret_cast<float4*>(ws);
#pragma unroll
    for (int j = 0; j < 2; ++j) {
        int row = row0 + j * 256;
#pragma unroll
        for (int g2 = 0; g2 < 4; ++g2)
            wsv[row * 4 + g2] =
                make_float4(acc[j][g2 * 4 + 0], acc[j][g2 * 4 + 1],
                            acc[j][g2 * 4 + 2], acc[j][g2 * 4 + 3]);
    }
}

// ======================= Kernel B: serial recurrence =======================
// 16 lanes per batch: lane = b_loc*16 + g*4 + i (g: 0=f,1=o,2=i,3=u).
// 4 batches/wave, 1 wave/block, 512 blocks. All cross-lane via DPP.
// Activations via short polynomials (only cos stays transcendental on chain).
extern "C" __global__ void __launch_bounds__(64)
recur_kernel(const float* __restrict__ ws,
             const float* __restrict__ Wf, const float* __restrict__ Wi,
             const float* __restrict__ Wu, const float* __restrict__ Wo,
             float* __restrict__ out)
{
    const int l  = threadIdx.x;
    const int bl = l >> 4;        // batch within wave
    const int r  = l & 15;
    const int g  = r >> 2;        // 0=f,1=o,2=i,3=u
    const int i  = r & 3;
    const int bg = blockIdx.x * 4 + bl;
    const bool m1 = (i >= 1), m2 = (i >= 2);

    const float* Wg = (g == 0) ? Wf : (g == 1) ? Wo : (g == 2) ? Wi : Wu;
    float wh0 = Wg[i * 36 + 32 + (i ^ 0)] * INV_PI;
    float wh1 = Wg[i * 36 + 32 + (i ^ 1)] * INV_PI;
    float wh2 = Wg[i * 36 + 32 + (i ^ 2)] * INV_PI;
    float wh3 = Wg[i * 36 + 32 + (i ^ 3)] * INV_PI;

    // gate activation: deg-3 poly on q in [0,1].
    //  g!=3: sigmoid(q);  g==3: tanh(q).  (Chebyshev-node fits, err <~1e-3)
    const bool isU = (g == 3);
    const float c0 = isU ? 0.0008346f : 0.499971f;
    const float c1 = isU ? 1.036967f  : 0.250882f;
    const float c2 = isU ? -0.175884f : -0.004115f;
    const float c3 = isU ? -0.099350f : -0.015724f;
    // tanh(c) for |c|<=2.08: c*P(c^2), P deg-4 (err <~2e-3 on range)
    const float T0 = 0.99827f,  T1 = -0.313542f, T2 = 0.0915168f,
                T3 = -0.0160296f, T4 = 0.0011677f;

    float ha = 0.f, hx1 = 0.f, hx2 = 0.f, hx3 = 0.f, cst = 0.f;

    const float* base = ws + (size_t)bg * 16 + r;
    const size_t TSTR = (size_t)NBATCH * 16;       // floats per timestep
    float* outb = out + (size_t)bg * 4 + r;        // valid when r<4

    auto qstep = [&](float xp, int t) {
        // pre-activation / pi (balanced tree)
        float A  = fmaf(wh0, ha,  xp);
        float Bt = fmaf(wh1, hx1, wh2 * hx2);
        float p  = fmaf(wh3, hx3, A) + Bt;
        // cos^2(pre) = 0.5 + 0.5*cos_rev(pre/pi)
        float fr = __builtin_amdgcn_fractf(p);
        float cs = __builtin_amdgcn_cosf(fr);
        float q  = fmaf(0.5f, cs, 0.5f);
        // prefix product over i within quad
        float s1 = qperm<0x90>(q);  q *= m1 ? s1 : 1.0f;
        float s2 = qperm<0x44>(q);  q *= m2 ? s2 : 1.0f;
        // per-lane activation poly (sigma / tanh on [0,1])
        float y  = fmaf(fmaf(fmaf(c3, q, c2), q, c1), q, c0);
        // combine at f-lanes
        float t1 = dpp_z<0x104>(y);          // f<-sig_o, i<-tanh_u
        float m_ = y * t1;                   // i-lanes: sig_i * tanh_u
        float t2 = dpp_z<0x108>(m_);         // f-lanes <- i*u
        cst = fmaf(y, cst, t2);              // f-lanes: f*c + i*u
        // tanh(c) via odd poly
        float tt = cst * cst;
        float gg = fmaf(fmaf(fmaf(fmaf(T4, tt, T3), tt, T2), tt, T1), tt, T0);
        float th = cst * gg;
        float hn = t1 * th;                  // o * tanh(c) at f-lanes
        if (r < 4) outb[(size_t)t * (NBATCH * 4)] = hn;
        // distribute h (lanes 0..3) to whole 16-row, then quad xor layout
        float d1 = dpp_k<0x114>(hn, hn);     // lanes 4..7  <- 0..3
        float d2 = dpp_k<0x118>(d1, d1);     // lanes 8..15 <- 0..7
        ha  = d2;
        hx1 = qperm<0xB1>(d2);               // xor 1
        hx2 = qperm<0x4E>(d2);               // xor 2
        hx3 = qperm<0x1B>(d2);               // xor 3 (single hop)
    };

    float xA[16], xB[16];
#pragma unroll
    for (int k = 0; k < 16; ++k) xA[k] = base[(size_t)k * TSTR];

    for (int it = 0; it < 4; ++it) {
        const int tb = it * 32;
#pragma unroll
        for (int k = 0; k < 16; ++k) xB[k] = base[(size_t)(tb + 16 + k) * TSTR];
#pragma unroll
        for (int k = 0; k < 16; ++k) qstep(xA[k], tb + k);
        if (it < 3) {
#pragma unroll
            for (int k = 0; k < 16; ++k) xA[k] = base[(size_t)(tb + 32 + k) * TSTR];
        }
#pragma unroll
        for (int k = 0; k < 16; ++k) qstep(xB[k], tb + 16 + k);
    }

    const size_t off = (size_t)TSTEPS * NBATCH * 4;
    if (r < 4) {
        out[off + (size_t)bg * 4 + r] = ha;                       // final hx
        out[off + (size_t)NBATCH * 4 + (size_t)bg * 4 + r] = cst; // final cx
    }
}

// =============== Fallback: fused kernel (used if ws too small) ===============
#define CHUNK  16
#define NCHUNK (TSTEPS / CHUNK)
#define BPB    16

extern "C" __global__ void __launch_bounds__(256)
qlstm_kernel(const float* __restrict__ x,
             const float* __restrict__ Wf, const float* __restrict__ bfp,
             const float* __restrict__ Wi, const float* __restrict__ bip,
             const float* __restrict__ Wu, const float* __restrict__ bup,
             const float* __restrict__ Wo, const float* __restrict__ bop,
             float* __restrict__ out)
{
    __shared__ float4 Wx4[16 * 8];
    __shared__ float  biasS[16];
    __shared__ float4 Xs[2][CHUNK * BPB * 4];

    const int tid = threadIdx.x;
    const int B0  = blockIdx.x * BPB;
    float* WxF = (float*)Wx4;

    for (int idx = tid; idx < 512; idx += 256) {
        int rr = idx >> 5, k = idx & 31;
        int i = rr >> 2, g = rr & 3;
        const float* W = (g == 0) ? Wf : (g == 1) ? Wi : (g == 2) ? Wu : Wo;
        WxF[rr * 32 + k] = W[i * 36 + k];
    }
    if (tid < 16) {
        int i = tid >> 2, g = tid & 3;
        const float* bp = (g == 0) ? bfp : (g == 1) ? bip : (g == 2) ? bup : bop;
        biasS[tid] = bp[i];
    }

    const int wb = tid >> 2, i = tid & 3;
    const int bg = B0 + wb;
    const bool m1 = (i >= 1), m2 = (i >= 2);
    float wh[4][4];
    float h0 = 0.f, h1 = 0.f, h2 = 0.f, h3 = 0.f, cst = 0.f;
    if (tid < 64) {
#pragma unroll
        for (int e = 0; e < 4; ++e) {
            int col = i * 36 + 32 + (i ^ e);
            wh[0][e] = Wf[col];
            wh[1][e] = Wi[col];
            wh[2][e] = Wu[col];
            wh[3][e] = Wo[col];
        }
    }
    __syncthreads();

    auto produce = [&](int c) {
        const int buf  = c & 1;
        const int ptid = tid - 64;
        for (int idx = ptid; idx < CHUNK * BPB; idx += 192) {
            int tl = idx >> 4, blq = idx & 15;
            size_t tb = (size_t)(c * CHUNK + tl) * NBATCH + (size_t)(B0 + blq);
            const float4* xv = reinterpret_cast<const float4*>(x + tb * DIN);
            float4 a[8];
#pragma unroll
            for (int k = 0; k < 8; ++k) a[k] = xv[k];
#pragma unroll
            for (int i2 = 0; i2 < 4; ++i2) {
                float acc[4];
#pragma unroll
                for (int gq = 0; gq < 4; ++gq) {
                    const int rr = i2 * 4 + gq;
                    float s = biasS[rr];
#pragma unroll
                    for (int k = 0; k < 8; ++k) {
                        float4 w = Wx4[rr * 8 + k];
                        s = fmaf(a[k].x, w.x, s);
                        s = fmaf(a[k].y, w.y, s);
                        s = fmaf(a[k].z, w.z, s);
                        s = fmaf(a[k].w, w.w, s);
                    }
                    acc[gq] = s;
                }
                Xs[buf][idx * 4 + i2] = make_float4(acc[0], acc[1], acc[2], acc[3]);
            }
        }
    };

    if (tid >= 64) produce(0);
    __syncthreads();

    for (int c = 0; c < NCHUNK; ++c) {
        if (tid >= 64) {
            if (c + 1 < NCHUNK) produce(c + 1);
        } else {
            const int buf = c & 1;
            for (int tl = 0; tl < CHUNK; ++tl) {
                const int t = c * CHUNK + tl;
                float4 xp = Xs[buf][(tl * BPB + wb) * 4 + i];
                float pf = fmaf(wh[0][0], h0, fmaf(wh[0][1], h1, fmaf(wh[0][2], h2, fmaf(wh[0][3], h3, xp.x))));
                float pg = fmaf(wh[1][0], h0, fmaf(wh[1][1], h1, fmaf(wh[1][2], h2, fmaf(wh[1][3], h3, xp.y))));
                float pu = fmaf(wh[2][0], h0, fmaf(wh[2][1], h1, fmaf(wh[2][2], h2, fmaf(wh[2][3], h3, xp.z))));
                float po = fmaf(wh[3][0], h0, fmaf(wh[3][1], h1, fmaf(wh[3][2], h2, fmaf(wh[3][3], h3, xp.w))));
                float qf = cos2(pf), qi = cos2(pg), qu = cos2(pu), qo = cos2(po);
                float s1;
                s1 = qperm<0x90>(qf); qf *= m1 ? s1 : 1.0f;
                s1 = qperm<0x90>(qi); qi *= m1 ? s1 : 1.0f;
                s1 = qperm<0x90>(qu); qu *= m1 ? s1 : 1.0f;
                s1 = qperm<0x90>(qo); qo *= m1 ? s1 : 1.0f;
                s1 = qperm<0x44>(qf); qf *= m2 ? s1 : 1.0f;
                s1 = qperm<0x44>(qi); qi *= m2 ? s1 : 1.0f;
                s1 = qperm<0x44>(qu); qu *= m2 ? s1 : 1.0f;
                s1 = qperm<0x44>(qo); qo *= m2 ? s1 : 1.0f;
                float fg = sigm(qf);
                float ig = sigm(qi);
                float ug = tanh_f(qu);
                float og = sigm(qo);
                cst = fmaf(fg, cst, ig * ug);
                float hn = og * tanh_f(cst);
                out[(size_t)t * (NBATCH * 4) + (size_t)bg * 4 + i] = hn;
                h0 = hn;
                h1 = qperm<0xB1>(hn);
                h2 = qperm<0x4E>(hn);
                h3 = qperm<0x1B>(hn);
            }
        }
        __syncthreads();
    }

    if (tid < 64) {
        const size_t off = (size_t)TSTEPS * NBATCH * 4;
        out[off + (size_t)bg * 4 + i] = h0;
        out[off + (size_t)NBATCH * 4 + (size_t)bg * 4 + i] = cst;
    }
}

extern "C" void kernel_launch(void* const* d_in, const int* in_sizes, int n_in,
                              void* d_out, int out_size, void* d_ws, size_t ws_size,
                              hipStream_t stream) {
    (void)in_sizes; (void)n_in; (void)out_size;
    const float* x  = (const float*)d_in[0];
    const float* Wf = (const float*)d_in[1];
    const float* bf = (const float*)d_in[2];
    // d_in[3] = pf: RZ phases drop out of the measurement -> unused
    const float* Wi = (const float*)d_in[4];
    const float* bi = (const float*)d_in[5];
    const float* Wu = (const float*)d_in[7];
    const float* bu = (const float*)d_in[8];
    const float* Wo = (const float*)d_in[10];
    const float* bo = (const float*)d_in[11];
    float* out = (float*)d_out;

    const size_t need = (size_t)NROWS * 16 * sizeof(float);   // 16.78 MB
    if (ws_size >= need) {
        float* ws = (float*)d_ws;
        hipLaunchKernelGGL(xproj_kernel, dim3(NROWS / 512), dim3(256), 0, stream,
                           x, Wf, bf, Wi, bi, Wu, bu, Wo, bo, ws);
        hipLaunchKernelGGL(recur_kernel, dim3(NBATCH / 4), dim3(64), 0, stream,
                           ws, Wf, Wi, Wu, Wo, out);
    } else {
        hipLaunchKernelGGL(qlstm_kernel, dim3(NBATCH / 16), dim3(256), 0, stream,
                           x, Wf, bf, Wi, bi, Wu, bu, Wo, bo, out);
    }
}

// Round 7
// 43.182 us; speedup vs baseline: 4.4037x; 1.0236x over previous
//
#include <hip/hip_runtime.h>

#define TSTEPS 128
#define NBATCH 2048
#define DIN    32
#define NROWS  (TSTEPS * NBATCH)
#define INV_PI 0.31830988618379067f

// ---- DPP helpers ----
template <int CTRL>
__device__ __forceinline__ float qperm(float v) {   // quad_perm, all lanes valid
    return __int_as_float(
        __builtin_amdgcn_mov_dpp(__float_as_int(v), CTRL, 0xF, 0xF, true));
}
template <int CTRL>
__device__ __forceinline__ float dpp_z(float v) {   // row shift, invalid -> 0
    return __int_as_float(__builtin_amdgcn_update_dpp(
        0, __float_as_int(v), CTRL, 0xF, 0xF, true));
}
template <int CTRL>
__device__ __forceinline__ float dpp_k(float oldv, float v) { // invalid -> keep old
    return __int_as_float(__builtin_amdgcn_update_dpp(
        __float_as_int(oldv), __float_as_int(v), CTRL, 0xF, 0xF, false));
}
// ctrl: quad_perm 0x00-0xFF; row_shl:N = 0x100+N; row_shr:N = 0x110+N.
// 0x1B = quad XOR-3.

__device__ __forceinline__ float rcp_f(float x) { return __builtin_amdgcn_rcpf(x); }
__device__ __forceinline__ float sigm(float q)  { return rcp_f(1.0f + __expf(-q)); }
__device__ __forceinline__ float tanh_f(float z){ return fmaf(2.0f, rcp_f(1.0f + __expf(-2.0f * z)), -1.0f); }
__device__ __forceinline__ float cos2(float x)  { float c = __cosf(x); return c * c; }

// ======================= Kernel A: x-projection GEMM =======================
// ws[row*16 + g2*4 + i] = (1/pi)*(b_g[i] + x[row,:] . W_g[i,0:32])
// gate order g2: 0=f, 1=o, 2=i, 3=u.   row = t*NBATCH + b
extern "C" __global__ void __launch_bounds__(256)
xproj_kernel(const float* __restrict__ x,
             const float* __restrict__ Wf, const float* __restrict__ bfp,
             const float* __restrict__ Wi, const float* __restrict__ bip,
             const float* __restrict__ Wu, const float* __restrict__ bup,
             const float* __restrict__ Wo, const float* __restrict__ bop,
             float* __restrict__ ws)
{
    __shared__ float4 WL[16 * 8];
    __shared__ float  bias[16];
    const int tid = threadIdx.x;
    float* WLf = (float*)WL;
    for (int idx = tid; idx < 512; idx += 256) {
        int rr = idx >> 5, k = idx & 31;
        int g2 = rr >> 2, i = rr & 3;
        const float* W = (g2 == 0) ? Wf : (g2 == 1) ? Wo : (g2 == 2) ? Wi : Wu;
        WLf[rr * 32 + k] = W[i * 36 + k] * INV_PI;
    }
    if (tid < 16) {
        int g2 = tid >> 2, i = tid & 3;
        const float* bp = (g2 == 0) ? bfp : (g2 == 1) ? bop : (g2 == 2) ? bip : bup;
        bias[tid] = bp[i] * INV_PI;
    }
    __syncthreads();

    const int row0 = blockIdx.x * 512 + tid;   // 2 rows/thread, stride 256
    const float4* xv = reinterpret_cast<const float4*>(x);
    float4 xa[2][8];
#pragma unroll
    for (int j = 0; j < 2; ++j) {
        int row = row0 + j * 256;
#pragma unroll
        for (int k = 0; k < 8; ++k) xa[j][k] = xv[row * 8 + k];
    }
    float acc[2][16];
#pragma unroll
    for (int rr = 0; rr < 16; ++rr) {
        float4 w[8];
#pragma unroll
        for (int k = 0; k < 8; ++k) w[k] = WL[rr * 8 + k];
#pragma unroll
        for (int j = 0; j < 2; ++j) {
            float s = bias[rr];
#pragma unroll
            for (int k = 0; k < 8; ++k) {
                s = fmaf(xa[j][k].x, w[k].x, s);
                s = fmaf(xa[j][k].y, w[k].y, s);
                s = fmaf(xa[j][k].z, w[k].z, s);
                s = fmaf(xa[j][k].w, w[k].w, s);
            }
            acc[j][rr] = s;
        }
    }
    float4* wsv = reinterpret_cast<float4*>(ws);
#pragma unroll
    for (int j = 0; j < 2; ++j) {
        int row = row0 + j * 256;
#pragma unroll
        for (int g2 = 0; g2 < 4; ++g2)
            wsv[row * 4 + g2] =
                make_float4(acc[j][g2 * 4 + 0], acc[j][g2 * 4 + 1],
                            acc[j][g2 * 4 + 2], acc[j][g2 * 4 + 3]);
    }
}

// ======================= Kernel B: serial recurrence =======================
// 16 lanes per batch: lane = bl*16 + g*4 + i (g: 0=f,1=o,2=i,3=u).
// 4 batches/wave, 1 wave/block, 512 blocks.
// Loop has ZERO global-memory ops: X pre-staged in LDS, outputs staged in LDS.
extern "C" __global__ void __launch_bounds__(64)
recur_kernel(const float* __restrict__ ws,
             const float* __restrict__ Wf, const float* __restrict__ Wi,
             const float* __restrict__ Wu, const float* __restrict__ Wo,
             float* __restrict__ out)
{
    __shared__ float Xls[TSTEPS * 64];    // 32 KB: [t][bl*16 + r]
    __shared__ float Ols[TSTEPS * 16];    // 8 KB:  [t][bl*4 + i]

    const int l  = threadIdx.x;
    const int bl = l >> 4;
    const int r  = l & 15;
    const int g  = r >> 2;                // 0=f,1=o,2=i,3=u
    const int i  = r & 3;
    const int B0g = blockIdx.x * 4;
    const int bg  = B0g + bl;
    const bool m1 = (i >= 1), m2 = (i >= 2);

    // ---- stage X slice into LDS: 2 rounds x 16 float4 per lane ----
    const float4* wsv = reinterpret_cast<const float4*>(ws);
    float4* Xls4 = reinterpret_cast<float4*>(Xls);
#pragma unroll
    for (int j = 0; j < 2; ++j) {
        float4 v[16];
#pragma unroll
        for (int m = 0; m < 16; ++m) {
            int f4 = j * 1024 + m * 64 + l;       // 0..2047
            int t = f4 >> 4, c4 = f4 & 15;
            v[m] = wsv[(size_t)t * (NBATCH * 4) + B0g * 4 + c4];
        }
#pragma unroll
        for (int m = 0; m < 16; ++m) Xls4[j * 1024 + m * 64 + l] = v[m];
    }

    const float* Wg = (g == 0) ? Wf : (g == 1) ? Wo : (g == 2) ? Wi : Wu;
    float wh0 = Wg[i * 36 + 32 + (i ^ 0)] * INV_PI;
    float wh1 = Wg[i * 36 + 32 + (i ^ 1)] * INV_PI;
    float wh2 = Wg[i * 36 + 32 + (i ^ 2)] * INV_PI;
    float wh3 = Wg[i * 36 + 32 + (i ^ 3)] * INV_PI;

    // gate activation: deg-3 poly on q in [0,1]. g!=3: sigmoid; g==3: tanh.
    const bool isU = (g == 3);
    const float c0 = isU ? 0.0008346f : 0.499971f;
    const float c1 = isU ? 1.036967f  : 0.250882f;
    const float c2 = isU ? -0.175884f : -0.004115f;
    const float c3 = isU ? -0.099350f : -0.015724f;
    // tanh(c) for |c|<=2.08: c*P(c^2), deg-4
    const float T0 = 0.99827f,  T1 = -0.313542f, T2 = 0.0915168f,
                T3 = -0.0160296f, T4 = 0.0011677f;

    float ha = 0.f, hx1 = 0.f, hx2 = 0.f, hx3 = 0.f, cst = 0.f;

    __syncthreads();   // LDS X visible across lanes

    auto qstep = [&](float xp, int t) {
        float A  = fmaf(wh0, ha,  xp);
        float Bt = fmaf(wh1, hx1, wh2 * hx2);
        float p  = fmaf(wh3, hx3, A) + Bt;
        float fr = __builtin_amdgcn_fractf(p);
        float cs = __builtin_amdgcn_cosf(fr);
        float q  = fmaf(0.5f, cs, 0.5f);
        float s1 = qperm<0x90>(q);  q *= m1 ? s1 : 1.0f;
        float s2 = qperm<0x44>(q);  q *= m2 ? s2 : 1.0f;
        float y  = fmaf(fmaf(fmaf(c3, q, c2), q, c1), q, c0);
        float t1 = dpp_z<0x104>(y);          // f<-sig_o, i<-tanh_u
        float m_ = y * t1;                   // i-lanes: sig_i * tanh_u
        float t2 = dpp_z<0x108>(m_);         // f-lanes <- i*u
        cst = fmaf(y, cst, t2);              // f-lanes: f*c + i*u
        float tt = cst * cst;
        float gg = fmaf(fmaf(fmaf(fmaf(T4, tt, T3), tt, T2), tt, T1), tt, T0);
        float th = cst * gg;
        float hn = t1 * th;                  // o * tanh(c) at f-lanes
        if (r < 4) Ols[t * 16 + bl * 4 + r] = hn;
        float d1 = dpp_k<0x114>(hn, hn);     // lanes 4..7  <- 0..3
        float d2 = dpp_k<0x118>(d1, d1);     // lanes 8..15 <- 0..7
        ha  = d2;
        hx1 = qperm<0xB1>(d2);
        hx2 = qperm<0x4E>(d2);
        hx3 = qperm<0x1B>(d2);
    };

    // 4-deep LDS->reg prefetch ring
    float xr[4];
#pragma unroll
    for (int k = 0; k < 4; ++k) xr[k] = Xls[k * 64 + l];

    for (int t0 = 0; t0 < TSTEPS; t0 += 4) {
#pragma unroll
        for (int k = 0; k < 4; ++k) {
            const int t = t0 + k;
            float xp = xr[k];
            int tn = t + 4;  if (tn > TSTEPS - 1) tn = TSTEPS - 1;
            xr[k] = Xls[tn * 64 + l];
            qstep(xp, t);
        }
    }

    __syncthreads();   // Ols complete

    // ---- flush outputs: 8 float4 per lane, coalesced ----
    float4* outv = reinterpret_cast<float4*>(out);
    const float4* Ols4 = reinterpret_cast<const float4*>(Ols);
#pragma unroll
    for (int m = 0; m < 8; ++m) {
        int f4 = m * 64 + l;                 // 0..511
        int t = f4 >> 2, q4 = f4 & 3;
        outv[(size_t)t * (NBATCH) + B0g + q4] = Ols4[f4];
    }

    const size_t off = (size_t)TSTEPS * NBATCH * 4;
    if (r < 4) {
        out[off + (size_t)bg * 4 + r] = ha;                       // final hx
        out[off + (size_t)NBATCH * 4 + (size_t)bg * 4 + r] = cst; // final cx
    }
}

// =============== Fallback: fused kernel (used if ws too small) ===============
#define CHUNK  16
#define NCHUNK (TSTEPS / CHUNK)
#define BPB    16

extern "C" __global__ void __launch_bounds__(256)
qlstm_kernel(const float* __restrict__ x,
             const float* __restrict__ Wf, const float* __restrict__ bfp,
             const float* __restrict__ Wi, const float* __restrict__ bip,
             const float* __restrict__ Wu, const float* __restrict__ bup,
             const float* __restrict__ Wo, const float* __restrict__ bop,
             float* __restrict__ out)
{
    __shared__ float4 Wx4[16 * 8];
    __shared__ float  biasS[16];
    __shared__ float4 Xs[2][CHUNK * BPB * 4];

    const int tid = threadIdx.x;
    const int B0  = blockIdx.x * BPB;
    float* WxF = (float*)Wx4;

    for (int idx = tid; idx < 512; idx += 256) {
        int rr = idx >> 5, k = idx & 31;
        int i = rr >> 2, g = rr & 3;
        const float* W = (g == 0) ? Wf : (g == 1) ? Wi : (g == 2) ? Wu : Wo;
        WxF[rr * 32 + k] = W[i * 36 + k];
    }
    if (tid < 16) {
        int i = tid >> 2, g = tid & 3;
        const float* bp = (g == 0) ? bfp : (g == 1) ? bip : (g == 2) ? bup : bop;
        biasS[tid] = bp[i];
    }

    const int wb = tid >> 2, i = tid & 3;
    const int bg = B0 + wb;
    const bool m1 = (i >= 1), m2 = (i >= 2);
    float wh[4][4];
    float h0 = 0.f, h1 = 0.f, h2 = 0.f, h3 = 0.f, cst = 0.f;
    if (tid < 64) {
#pragma unroll
        for (int e = 0; e < 4; ++e) {
            int col = i * 36 + 32 + (i ^ e);
            wh[0][e] = Wf[col];
            wh[1][e] = Wi[col];
            wh[2][e] = Wu[col];
            wh[3][e] = Wo[col];
        }
    }
    __syncthreads();

    auto produce = [&](int c) {
        const int buf  = c & 1;
        const int ptid = tid - 64;
        for (int idx = ptid; idx < CHUNK * BPB; idx += 192) {
            int tl = idx >> 4, blq = idx & 15;
            size_t tb = (size_t)(c * CHUNK + tl) * NBATCH + (size_t)(B0 + blq);
            const float4* xv = reinterpret_cast<const float4*>(x + tb * DIN);
            float4 a[8];
#pragma unroll
            for (int k = 0; k < 8; ++k) a[k] = xv[k];
#pragma unroll
            for (int i2 = 0; i2 < 4; ++i2) {
                float acc[4];
#pragma unroll
                for (int gq = 0; gq < 4; ++gq) {
                    const int rr = i2 * 4 + gq;
                    float s = biasS[rr];
#pragma unroll
                    for (int k = 0; k < 8; ++k) {
                        float4 w = Wx4[rr * 8 + k];
                        s = fmaf(a[k].x, w.x, s);
                        s = fmaf(a[k].y, w.y, s);
                        s = fmaf(a[k].z, w.z, s);
                        s = fmaf(a[k].w, w.w, s);
                    }
                    acc[gq] = s;
                }
                Xs[buf][idx * 4 + i2] = make_float4(acc[0], acc[1], acc[2], acc[3]);
            }
        }
    };

    if (tid >= 64) produce(0);
    __syncthreads();

    for (int c = 0; c < NCHUNK; ++c) {
        if (tid >= 64) {
            if (c + 1 < NCHUNK) produce(c + 1);
        } else {
            const int buf = c & 1;
            for (int tl = 0; tl < CHUNK; ++tl) {
                const int t = c * CHUNK + tl;
                float4 xp = Xs[buf][(tl * BPB + wb) * 4 + i];
                float pf = fmaf(wh[0][0], h0, fmaf(wh[0][1], h1, fmaf(wh[0][2], h2, fmaf(wh[0][3], h3, xp.x))));
                float pg = fmaf(wh[1][0], h0, fmaf(wh[1][1], h1, fmaf(wh[1][2], h2, fmaf(wh[1][3], h3, xp.y))));
                float pu = fmaf(wh[2][0], h0, fmaf(wh[2][1], h1, fmaf(wh[2][2], h2, fmaf(wh[2][3], h3, xp.z))));
                float po = fmaf(wh[3][0], h0, fmaf(wh[3][1], h1, fmaf(wh[3][2], h2, fmaf(wh[3][3], h3, xp.w))));
                float qf = cos2(pf), qi = cos2(pg), qu = cos2(pu), qo = cos2(po);
                float s1;
                s1 = qperm<0x90>(qf); qf *= m1 ? s1 : 1.0f;
                s1 = qperm<0x90>(qi); qi *= m1 ? s1 : 1.0f;
                s1 = qperm<0x90>(qu); qu *= m1 ? s1 : 1.0f;
                s1 = qperm<0x90>(qo); qo *= m1 ? s1 : 1.0f;
                s1 = qperm<0x44>(qf); qf *= m2 ? s1 : 1.0f;
                s1 = qperm<0x44>(qi); qi *= m2 ? s1 : 1.0f;
                s1 = qperm<0x44>(qu); qu *= m2 ? s1 : 1.0f;
                s1 = qperm<0x44>(qo); qo *= m2 ? s1 : 1.0f;
                float fg = sigm(qf);
                float ig = sigm(qi);
                float ug = tanh_f(qu);
                float og = sigm(qo);
                cst = fmaf(fg, cst, ig * ug);
                float hn = og * tanh_f(cst);
                out[(size_t)t * (NBATCH * 4) + (size_t)bg * 4 + i] = hn;
                h0 = hn;
                h1 = qperm<0xB1>(hn);
                h2 = qperm<0x4E>(hn);
                h3 = qperm<0x1B>(hn);
            }
        }
        __syncthreads();
    }

    if (tid < 64) {
        const size_t off = (size_t)TSTEPS * NBATCH * 4;
        out[off + (size_t)bg * 4 + i] = h0;
        out[off + (size_t)NBATCH * 4 + (size_t)bg * 4 + i] = cst;
    }
}

extern "C" void kernel_launch(void* const* d_in, const int* in_sizes, int n_in,
                              void* d_out, int out_size, void* d_ws, size_t ws_size,
                              hipStream_t stream) {
    (void)in_sizes; (void)n_in; (void)out_size;
    const float* x  = (const float*)d_in[0];
    const float* Wf = (const float*)d_in[1];
    const float* bf = (const float*)d_in[2];
    // d_in[3] = pf: RZ phases drop out of the measurement -> unused
    const float* Wi = (const float*)d_in[4];
    const float* bi = (const float*)d_in[5];
    const float* Wu = (const float*)d_in[7];
    const float* bu = (const float*)d_in[8];
    const float* Wo = (const float*)d_in[10];
    const float* bo = (const float*)d_in[11];
    float* out = (float*)d_out;

    const size_t need = (size_t)NROWS * 16 * sizeof(float);   // 16.78 MB
    if (ws_size >= need) {
        float* ws = (float*)d_ws;
        hipLaunchKernelGGL(xproj_kernel, dim3(NROWS / 512), dim3(256), 0, stream,
                           x, Wf, bf, Wi, bi, Wu, bu, Wo, bo, ws);
        hipLaunchKernelGGL(recur_kernel, dim3(NBATCH / 4), dim3(64), 0, stream,
                           ws, Wf, Wi, Wu, Wo, out);
    } else {
        hipLaunchKernelGGL(qlstm_kernel, dim3(NBATCH / 16), dim3(256), 0, stream,
                           x, Wf, bf, Wi, bi, Wu, bu, Wo, bo, out);
    }
}